// Round 3
// 835.430 us; speedup vs baseline: 1.0796x; 1.0796x over previous
//
#include <hip/hip_runtime.h>
#include <math.h>

#define NBATCH 256
#define CDIM   384

typedef __attribute__((ext_vector_type(4))) float  f32x4;
typedef __attribute__((ext_vector_type(8))) __bf16 bf16x8;
typedef __attribute__((ext_vector_type(4))) __bf16 bf16x4;

__device__ __forceinline__ void load16(const void* g, void* l) {
    __builtin_amdgcn_global_load_lds(
        (const __attribute__((address_space(1))) void*)g,
        (__attribute__((address_space(3))) void*)l, 16, 0, 0);
}

// ---------------------------------------------------------------------------
// Gather: target (B,576,384) fp32 -> ta (B,144,384) bf16, pixel-major. float4.
// ---------------------------------------------------------------------------
__global__ __launch_bounds__(256) void gather_bf16(
    const float* __restrict__ target,
    const float* __restrict__ bbox,
    __bf16* __restrict__ ta)
{
    const int b = blockIdx.x, t = threadIdx.x;
    __shared__ int pos[144];

    if (t < 144) {
        const float bx0 = bbox[b * 4 + 0] * 24.f;
        const float by0 = bbox[b * 4 + 1] * 24.f;
        const float bw  = bbox[b * 4 + 2] * 24.f;
        const float bh  = bbox[b * 4 + 3] * 24.f;
        const float l0 = (bw + bh) * 0.5f;
        const float l  = sqrtf((bw + l0) * (bh + l0));
        const int xmin = (int)fminf(fmaxf(ceilf (bx0 - l * 0.5f), 0.f), 23.f);
        const int ymin = (int)fminf(fmaxf(ceilf (by0 - l * 0.5f), 0.f), 23.f);
        const int xmax = (int)fminf(fmaxf(truncf(bx0 + l * 0.5f), 0.f), 23.f);
        const int ymax = (int)fminf(fmaxf(truncf(by0 + l * 0.5f), 0.f), 23.f);
        const int i = t / 12, j = t % 12;
        int r = ymin + (i * (ymax - ymin)) / 12;
        int c = xmin + (j * (xmax - xmin)) / 12;
        r = min(max(r, 0), 23);
        c = min(max(c, 0), 23);
        pos[t] = r * 24 + c;
    }
    __syncthreads();

    const float* tb  = target + (size_t)b * 576 * 384;
    __bf16*      tab = ta     + (size_t)b * 144 * 384;
    for (int idx = t; idx < 144 * 96; idx += 256) {
        const int p = idx / 96, c4 = idx - p * 96;
        const float4 v = *(const float4*)&tb[(size_t)pos[p] * 384 + c4 * 4];
        bf16x4 o = { (__bf16)v.x, (__bf16)v.y, (__bf16)v.z, (__bf16)v.w };
        *(bf16x4*)&tab[(size_t)p * 384 + c4 * 4] = o;
    }
}

// ---------------------------------------------------------------------------
// Weight prep (coalesced both sides): W (oc, ic, taps) fp32 -> Wt (oc, tap, ic)
// bf16, one oc per block, transpose through LDS.
// ---------------------------------------------------------------------------
template <int TAPS>
__global__ __launch_bounds__(256) void prep_w(
    const float* __restrict__ W, __bf16* __restrict__ Wt)
{
    const int K = TAPS * 384;
    __shared__ float ws[TAPS * 384];
    const int oc = blockIdx.x;
    const float* src = W + (size_t)oc * K;
    for (int i = threadIdx.x; i < K; i += 256) ws[i] = src[i];
    __syncthreads();
    __bf16* dst = Wt + (size_t)oc * K;
    for (int i = threadIdx.x; i < K; i += 256) {
        const int tap = i / 384;
        const int ic  = i - tap * 384;
        dst[i] = (__bf16)ws[ic * TAPS + tap];
    }
}

// ---------------------------------------------------------------------------
// Implicit-GEMM conv (tap-decomposed) + BN + leaky (+ residual).
// A: (B*144, 384) bf16 pixel-major.  Wt: (384, TAPS*384) bf16.
// BM=BN=128, BK=32, 4 waves (64x64 each, 4x4 mfma 16x16x32).
// Counted-vmcnt depth-2 pipeline: TRIPLE-buffered LDS, raw s_barrier (no
// compiler vmcnt(0) drain), s_waitcnt vmcnt(4) keeps next tile's 4
// global_load_lds in flight across the barrier. XOR-swizzled LDS
// (conflict-free).  + T5 s_setprio around MFMA cluster (role-split exists
// in this schedule).  [rounds 1-2 were container acquisition failures]
// ---------------------------------------------------------------------------
template <int TAPS, int KW, int PAD, bool RESID>
__global__ __launch_bounds__(256, 3) void conv_mfma(
    const __bf16* __restrict__ A,
    const __bf16* __restrict__ Wt,
    const float* __restrict__ gg, const float* __restrict__ bb,
    const float* __restrict__ mm, const float* __restrict__ vv,
    const float* __restrict__ temp,
    void* __restrict__ outp)
{
    const int K  = TAPS * 384;
    const int IT = TAPS * 12;          // K-iterations of 32 (300 or 108; %3==0)
    const int m0 = blockIdx.x * 128;
    const int n0 = blockIdx.y * 128;
    const int t  = threadIdx.x;
    const int lane  = t & 63, w = t >> 6;
    const int wm    = (w & 1) * 64, wn = (w >> 1) * 64;
    const int col16 = lane & 15,  quad = lane >> 4;

    __shared__ __bf16 As0[128 * 32], As1[128 * 32], As2[128 * 32];
    __shared__ __bf16 Bs0[128 * 32], Bs1[128 * 32], Bs2[128 * 32];

    // staging: thread t owns 16B slot t (rows r0, r0+64); swizzled k-group
    const int r0   = t >> 2, slot = t & 3;
    const int kg   = slot ^ ((r0 >> 1) & 3);
    const int mrow0 = m0 + r0, mrow1 = m0 + r0 + 64;
    const int b0 = mrow0 / 144, p0 = mrow0 - b0 * 144;
    const int b1 = mrow1 / 144, p1 = mrow1 - b1 * 144;
    const int y0 = p0 / 12, x0 = p0 - y0 * 12;
    const int y1 = p1 / 12, x1 = p1 - y1 * 12;
    const __bf16* Ab0 = A + (size_t)b0 * 144 * 384 + kg * 8;
    const __bf16* Ab1 = A + (size_t)b1 * 144 * 384 + kg * 8;

    // loop-invariant swizzled LDS read offsets (elements)
    int offA[4], offB[4];
#pragma unroll
    for (int mi = 0; mi < 4; ++mi) {
        const int r = wm + mi * 16 + col16;
        offA[mi] = r * 32 + (quad ^ ((r >> 1) & 3)) * 8;
    }
#pragma unroll
    for (int ni = 0; ni < 4; ++ni) {
        const int r = wn + ni * 16 + col16;
        offB[ni] = r * 32 + (quad ^ ((r >> 1) & 3)) * 8;
    }

    f32x4 acc[4][4];
#pragma unroll
    for (int mi = 0; mi < 4; ++mi)
#pragma unroll
        for (int ni = 0; ni < 4; ++ni)
            acc[mi][ni] = (f32x4){0.f, 0.f, 0.f, 0.f};

    // issue-state: (jn, tapn, pointers) always describe tile `next`
    int jn = 0, tapn = 0, next = 0;
    const __bf16* aT0;
    const __bf16* aT1;
    {   // tap 0 bases
        const int sy0 = min(max(y0 - PAD, 0), 11), sx0 = min(max(x0 - PAD, 0), 11);
        const int sy1 = min(max(y1 - PAD, 0), 11), sx1 = min(max(x1 - PAD, 0), 11);
        aT0 = Ab0 + (size_t)(sy0 * 12 + sx0) * 384;
        aT1 = Ab1 + (size_t)(sy1 * 12 + sx1) * 384;
    }
    const __bf16* bT0 = Wt + (size_t)(n0 + r0)      * K + kg * 8;
    const __bf16* bT1 = Wt + (size_t)(n0 + r0 + 64) * K + kg * 8;

    auto issue = [&](__bf16* SA, __bf16* SB) {
        load16(aT0 + jn * 32, &SA[t * 8]);
        load16(aT1 + jn * 32, &SA[(t + 256) * 8]);
        load16(bT0 + jn * 32, &SB[t * 8]);
        load16(bT1 + jn * 32, &SB[(t + 256) * 8]);
    };
    auto advance = [&]() {
        if (++jn == 12) {
            jn = 0;
            ++tapn;
            if (tapn < TAPS) {
                const int ky = tapn / KW - PAD, kx = tapn % KW - PAD;
                const int sy0 = min(max(y0 + ky, 0), 11), sx0 = min(max(x0 + kx, 0), 11);
                const int sy1 = min(max(y1 + ky, 0), 11), sx1 = min(max(x1 + kx, 0), 11);
                aT0 = Ab0 + (size_t)(sy0 * 12 + sx0) * 384;
                aT1 = Ab1 + (size_t)(sy1 * 12 + sx1) * 384;
                bT0 += 384;
                bT1 += 384;
            }
        }
    };
    // One pipeline step: consume tile in (SA,SB), prefetch tile next -> (NA,NB_).
    // vmcnt(4): wait current tile's 4 loads, keep following tile's 4 in flight.
    auto step = [&](const __bf16* SA, const __bf16* SB,
                    __bf16* NA, __bf16* NB_, bool last) {
        if (last) asm volatile("s_waitcnt vmcnt(0)" ::: "memory");
        else      asm volatile("s_waitcnt vmcnt(4)" ::: "memory");
        __builtin_amdgcn_s_barrier();
        __builtin_amdgcn_sched_barrier(0);
        if (next < IT) { issue(NA, NB_); advance(); ++next; }
        bf16x8 av[4], bv[4];
#pragma unroll
        for (int mi = 0; mi < 4; ++mi) av[mi] = *(const bf16x8*)&SA[offA[mi]];
#pragma unroll
        for (int ni = 0; ni < 4; ++ni) bv[ni] = *(const bf16x8*)&SB[offB[ni]];
        __builtin_amdgcn_s_setprio(1);
#pragma unroll
        for (int mi = 0; mi < 4; ++mi)
#pragma unroll
            for (int ni = 0; ni < 4; ++ni)
                acc[mi][ni] = __builtin_amdgcn_mfma_f32_16x16x32_bf16(
                    av[mi], bv[ni], acc[mi][ni], 0, 0, 0);
        __builtin_amdgcn_s_setprio(0);
    };

    // prologue: tiles 0 and 1 in flight
    issue(As0, Bs0); advance(); ++next;
    issue(As1, Bs1); advance(); ++next;

    for (int it3 = 0; it3 < IT; it3 += 3) {
        step(As0, Bs0, As2, Bs2, it3 + 1 == IT);
        step(As1, Bs1, As0, Bs0, it3 + 2 == IT);
        step(As2, Bs2, As1, Bs1, it3 + 3 == IT);
    }

    // Epilogue: BN + leaky (+ residual).  D: row = quad*4+reg, col = lane&15.
#pragma unroll
    for (int ni = 0; ni < 4; ++ni) {
        const int gn = n0 + wn + ni * 16 + col16;
        const float scale = gg[gn] * rsqrtf(vv[gn] + 1e-5f);
        const float shift = bb[gn] - mm[gn] * scale;
        if (!RESID) {
            __bf16* h1 = (__bf16*)outp;
#pragma unroll
            for (int mi = 0; mi < 4; ++mi) {
                const int gm = m0 + wm + mi * 16 + quad * 4;
#pragma unroll
                for (int r = 0; r < 4; ++r) {
                    float v = acc[mi][ni][r] * scale + shift;
                    v = (v >= 0.f) ? v : 0.01f * v;
                    h1[(size_t)(gm + r) * 384 + gn] = (__bf16)v;
                }
            }
        } else {
            float* outF = (float*)outp;
#pragma unroll
            for (int mi = 0; mi < 4; ++mi) {
                const int gm = m0 + wm + mi * 16 + quad * 4;
#pragma unroll
                for (int r = 0; r < 4; ++r) {
                    float v = acc[mi][ni][r] * scale + shift;
                    v = (v >= 0.f) ? v : 0.01f * v;
                    outF[(size_t)(gm + r) * 384 + gn] =
                        temp[(size_t)(gm + r) * 384 + gn] + v;
                }
            }
        }
    }
}

// ---------------------------------------------------------------------------
extern "C" void kernel_launch(void* const* d_in, const int* in_sizes, int n_in,
                              void* d_out, int out_size, void* d_ws, size_t ws_size,
                              hipStream_t stream) {
    const float* temp   = (const float*)d_in[0];
    const float* target = (const float*)d_in[1];
    const float* bbox   = (const float*)d_in[2];
    const float* W1     = (const float*)d_in[3];
    const float* g1     = (const float*)d_in[4];
    const float* b1     = (const float*)d_in[5];
    const float* m1     = (const float*)d_in[6];
    const float* v1     = (const float*)d_in[7];
    const float* W2     = (const float*)d_in[8];
    const float* g2     = (const float*)d_in[9];
    const float* b2     = (const float*)d_in[10];
    const float* m2     = (const float*)d_in[11];
    const float* v2     = (const float*)d_in[12];
    float* out = (float*)d_out;

    __bf16* ta  = (__bf16*)d_ws;                          // 256*144*384
    __bf16* h1  = ta  + (size_t)NBATCH * 144 * CDIM;      // 256*144*384
    __bf16* Wt1 = h1  + (size_t)NBATCH * 144 * CDIM;      // 384*25*384
    __bf16* Wt2 = Wt1 + (size_t)CDIM * 25 * CDIM;         // 384*9*384

    prep_w<25><<<dim3(CDIM), dim3(256), 0, stream>>>(W1, Wt1);
    prep_w<9><<<dim3(CDIM), dim3(256), 0, stream>>>(W2, Wt2);
    gather_bf16<<<dim3(NBATCH), dim3(256), 0, stream>>>(target, bbox, ta);

    // M = 256*144 = 36864 = 288*128 ; N = 384 = 3*128
    conv_mfma<25, 5, 2, false><<<dim3(288, 3), dim3(256), 0, stream>>>(
        ta, Wt1, g1, b1, m1, v1, nullptr, (void*)h1);
    conv_mfma<9, 3, 1, true><<<dim3(288, 3), dim3(256), 0, stream>>>(
        h1, Wt2, g2, b2, m2, v2, temp, (void*)out);
}